// Round 7
// baseline (240.327 us; speedup 1.0000x reference)
//
#include <hip/hip_runtime.h>
#include <cstdint>
#include <cstddef>

#define B_ 4
#define T_ 2048
#define C_ 1024
#define M_ (B_ * T_)   // 8192 rows
#define HALF_ 8
#define W_ 17
#define QKV_STRIDE 3072

typedef unsigned short u16;
typedef _Float16 half8 __attribute__((ext_vector_type(8)));
typedef _Float16 half2_t __attribute__((ext_vector_type(2)));
typedef float f32x16 __attribute__((ext_vector_type(16)));

__device__ __forceinline__ float dot16(half8 a, half8 b, float acc) {
#if __has_builtin(__builtin_amdgcn_fdot2)
    const half2_t* pa = (const half2_t*)&a;
    const half2_t* pb = (const half2_t*)&b;
#pragma unroll
    for (int e = 0; e < 4; ++e) acc = __builtin_amdgcn_fdot2(pa[e], pb[e], acc, false);
#else
#pragma unroll
    for (int e = 0; e < 8; ++e) acc += (float)a[e] * (float)b[e];
#endif
    return acc;
}

__device__ __forceinline__ ushort4 cvt4(float4 v) {
    ushort4 o;
    _Float16 a = (_Float16)v.x; o.x = __builtin_bit_cast(unsigned short, a);
    _Float16 b = (_Float16)v.y; o.y = __builtin_bit_cast(unsigned short, b);
    _Float16 c = (_Float16)v.z; o.z = __builtin_bit_cast(unsigned short, c);
    _Float16 d = (_Float16)v.w; o.w = __builtin_bit_cast(unsigned short, d);
    return o;
}

// ---------------- prologue: x fp32->fp16 + bias concat ----------------
__global__ void prologue(const float* __restrict__ x,
                         const float* __restrict__ bq, const float* __restrict__ bk,
                         const float* __restrict__ bv,
                         u16* __restrict__ xh, float* __restrict__ bcat) {
    const int blk = blockIdx.x;
    if (blk >= 8192) {   // bias concat: 12 blocks
        int i = (blk - 8192) * 256 + threadIdx.x;     // 0..3071
        const float* src = (i < 1024) ? bq : (i < 2048) ? bk : bv;
        bcat[i] = src[i & 1023];
        return;
    }
    int j = blk * 256 + threadIdx.x;
    ((ushort4*)xh)[j] = cvt4(((const float4*)x)[j]);
}

// ---------------- weight converter: fp32 -> fp16 FRAGMENT-MAJOR ----------------
// B-frag for mfma_f32_32x32x16 (NT): lane l holds Bw[n = nt*32 + (l&31)]
// [k = ks*16 + (l>>5)*8 + e], e=0..7. Chunk (nt,ks) = 64 lanes x 8 halves
// contiguous: out[((nt*64 + ks)*64 + lane)*8 + e].
// QKV: ntiles 0..95 (Wq 0-31, Wk 32-63, Wv 64-95) -> wfq. Wo: 0..31 -> wfo.
__global__ void wfrag(const float* __restrict__ Wq, const float* __restrict__ Wk,
                      const float* __restrict__ Wv, const float* __restrict__ Wo,
                      u16* __restrict__ wfq, u16* __restrict__ wfo) {
    int c = blockIdx.x * 256 + threadIdx.x;   // 524288 chunks total
    const float* src;
    u16* dst;
    int cc;
    if (c < 393216) {        // QKV: 3 mats x 131072 chunks
        int mat = c / 131072;
        src = (mat == 0) ? Wq : (mat == 1) ? Wk : Wv;
        dst = wfq;  cc = c;  c = c % 131072;
    } else {
        src = Wo;  dst = wfo;  cc = c - 393216;  c = cc;
    }
    const int nt_local = c >> 12;            // /4096 (chunks per 32-row tile)
    const int ks   = (c >> 6) & 63;
    const int lane = c & 63;
    const int row = nt_local * 32 + (lane & 31);
    const int col = ks * 16 + (lane >> 5) * 8;
    const float4* s = (const float4*)(src + (size_t)row * C_ + col);
    ushort4 lo = cvt4(s[0]);
    ushort4 hi = cvt4(s[1]);
    ushort4* d = (ushort4*)(dst + (size_t)cc * 8);
    d[0] = lo;
    d[1] = hi;
}

// ---------------- QKV GEMM: 128x128 tile, BK=32, 32x32x16 MFMA ----------------
// A staged via register-prefetch -> LDS (8 KB). B read DIRECTLY from global in
// fragment-major layout (one coalesced dwordx4 per frag) — no LDS for B.
// Halves LDS traffic vs R6 (was LDS-throughput-bound: 48KB/block-iter ~ 45us/CU).
__global__ __launch_bounds__(256) void gemm_nt_bfrag(
    const u16* __restrict__ A, const u16* __restrict__ Bfrag,
    const float* __restrict__ bias, u16* __restrict__ Cout,
    int Ndim, int Kdim)
{
    __shared__ __align__(16) u16 As[128 * 32];

    const int tid  = threadIdx.x;
    const int lane = tid & 63;
    const int wave = tid >> 6;
    const int m0 = blockIdx.y * 128;
    const int n0 = blockIdx.x * 128;
    const int wm = (wave >> 1) * 64;
    const int wnt = blockIdx.x * 4 + (wave & 1) * 2;   // wave's base n-tile (32-wide)

    const int srow = wave * 32 + (lane >> 2);
    const int kc = ((lane & 3) ^ ((lane >> 3) & 3)) * 8;
    const u16* Ap = A + (size_t)(m0 + srow) * Kdim + kc;
    const size_t skip16 = (size_t)16 * Kdim;
    u16* AsL = As + wave * 1024 + lane * 8;

    const int nks = Kdim >> 4;   // k-steps total
    // B-frag base pointers for this wave's two n-tiles
    const u16* Bf0 = Bfrag + ((size_t)(wnt + 0) * nks) * 512 + lane * 8;
    const u16* Bf1 = Bfrag + ((size_t)(wnt + 1) * nks) * 512 + lane * 8;

    f32x16 acc[2][2];
#pragma unroll
    for (int i = 0; i < 2; ++i)
#pragma unroll
        for (int j = 0; j < 2; ++j)
#pragma unroll
            for (int r = 0; r < 16; ++r) acc[i][j][r] = 0.f;

    const int rr = lane & 31;
    const int hi = lane >> 5;
    const int sw = (lane >> 1) & 3;

    uint4 pa0 = *(const uint4*)(Ap);
    uint4 pa1 = *(const uint4*)(Ap + skip16);

    for (int k0 = 0; k0 < Kdim; k0 += 32) {
        const int ks = k0 >> 4;
        // B frags for this iter: pure global, no LDS dep — issue before barriers
        half8 bfr[2][2];
        bfr[0][0] = *(const half8*)(Bf0 + (size_t)ks * 512);
        bfr[0][1] = *(const half8*)(Bf1 + (size_t)ks * 512);
        bfr[1][0] = *(const half8*)(Bf0 + (size_t)(ks + 1) * 512);
        bfr[1][1] = *(const half8*)(Bf1 + (size_t)(ks + 1) * 512);

        if (k0) __syncthreads();
        *(uint4*)(AsL)       = pa0;
        *(uint4*)(AsL + 512) = pa1;
        __syncthreads();

        if (k0 + 32 < Kdim) {
            pa0 = *(const uint4*)(Ap + k0 + 32);
            pa1 = *(const uint4*)(Ap + k0 + 32 + skip16);
        }

#pragma unroll
        for (int kk = 0; kk < 2; ++kk) {
            const int slot = ((kk * 2 + hi) ^ sw) * 8;
            half8 af[2];
#pragma unroll
            for (int i = 0; i < 2; ++i)
                af[i] = *(const half8*)&As[(wm + i * 32 + rr) * 32 + slot];
#pragma unroll
            for (int i = 0; i < 2; ++i)
#pragma unroll
                for (int j = 0; j < 2; ++j)
                    acc[i][j] = __builtin_amdgcn_mfma_f32_32x32x16_f16(af[i], bfr[kk][j], acc[i][j], 0, 0, 0);
        }
    }

    // C/D: col = lane&31, row = (reg&3) + 8*(reg>>2) + 4*(lane>>5)  [m74/m101]
#pragma unroll
    for (int i = 0; i < 2; ++i) {
#pragma unroll
        for (int j = 0; j < 2; ++j) {
            const int col = (wnt + j) * 32 + (lane & 31);
            const float bv = bias[col];
#pragma unroll
            for (int reg = 0; reg < 16; ++reg) {
                const int row = m0 + wm + i * 32 + (reg & 3) + 8 * (reg >> 2) + 4 * (lane >> 5);
                _Float16 h = (_Float16)(acc[i][j][reg] + bv);
                Cout[(size_t)row * Ndim + col] = __builtin_bit_cast(unsigned short, h);
            }
        }
    }
}

// ---------------- Wo GEMM: 128x64 tile, BK=32, B fragment-direct, fp32 out ----
__global__ __launch_bounds__(256) void gemm_nt_64_bfrag(
    const u16* __restrict__ A, const u16* __restrict__ Bfrag,
    const float* __restrict__ bias, float* __restrict__ Cout,
    int Ndim, int Kdim)
{
    __shared__ __align__(16) u16 As[128 * 32];

    const int tid  = threadIdx.x;
    const int lane = tid & 63;
    const int wave = tid >> 6;
    const int m0 = blockIdx.y * 128;
    const int wm = (wave >> 1) * 64;
    const int wnt = blockIdx.x * 2 + (wave & 1);   // n-tile (32-wide)

    const int srow = wave * 32 + (lane >> 2);
    const int kc = ((lane & 3) ^ ((lane >> 3) & 3)) * 8;
    const u16* Ap = A + (size_t)(m0 + srow) * Kdim + kc;
    const size_t skip16 = (size_t)16 * Kdim;
    u16* AsL = As + wave * 1024 + lane * 8;

    const int nks = Kdim >> 4;
    const u16* Bf = Bfrag + ((size_t)wnt * nks) * 512 + lane * 8;

    f32x16 acc[2];
#pragma unroll
    for (int i = 0; i < 2; ++i)
#pragma unroll
        for (int r = 0; r < 16; ++r) acc[i][r] = 0.f;

    const int rr = lane & 31;
    const int hi = lane >> 5;
    const int sw = (lane >> 1) & 3;

    uint4 pa0 = *(const uint4*)(Ap);
    uint4 pa1 = *(const uint4*)(Ap + skip16);

    for (int k0 = 0; k0 < Kdim; k0 += 32) {
        const int ks = k0 >> 4;
        half8 bfr[2];
        bfr[0] = *(const half8*)(Bf + (size_t)ks * 512);
        bfr[1] = *(const half8*)(Bf + (size_t)(ks + 1) * 512);

        if (k0) __syncthreads();
        *(uint4*)(AsL)       = pa0;
        *(uint4*)(AsL + 512) = pa1;
        __syncthreads();

        if (k0 + 32 < Kdim) {
            pa0 = *(const uint4*)(Ap + k0 + 32);
            pa1 = *(const uint4*)(Ap + k0 + 32 + skip16);
        }

#pragma unroll
        for (int kk = 0; kk < 2; ++kk) {
            const int slot = ((kk * 2 + hi) ^ sw) * 8;
#pragma unroll
            for (int i = 0; i < 2; ++i) {
                half8 af = *(const half8*)&As[(wm + i * 32 + rr) * 32 + slot];
                acc[i] = __builtin_amdgcn_mfma_f32_32x32x16_f16(af, bfr[kk], acc[i], 0, 0, 0);
            }
        }
    }

    const int col = wnt * 32 + (lane & 31);
    const float bv = bias[col];
#pragma unroll
    for (int i = 0; i < 2; ++i) {
#pragma unroll
        for (int reg = 0; reg < 16; ++reg) {
            const int row = m0 + wm + i * 32 + (reg & 3) + 8 * (reg >> 2) + 4 * (lane >> 5);
            Cout[(size_t)row * Ndim + col] = acc[i][reg] + bv;
        }
    }
}

// ---------------- windowed attention: one wave per token, branchless ----
__global__ __launch_bounds__(256) void attn_local(
    const u16* __restrict__ qkv, u16* __restrict__ ctx)
{
    const int wid  = blockIdx.x * 4 + (threadIdx.x >> 6);
    const int lane = threadIdx.x & 63;
    const int b = wid >> 11;
    const int t = wid & (T_ - 1);
    const int base = b * T_;
    const size_t qrow = (size_t)(base + t) * QKV_STRIDE;
    const int c0 = lane * 8;

    half8 q0 = *(const half8*)(qkv + qrow + c0);
    half8 q1 = *(const half8*)(qkv + qrow + 512 + c0);

    float s[W_];
#pragma unroll
    for (int o = 0; o < W_; ++o) {
        int j = t - HALF_ + o;
        int jc = min(max(j, 0), T_ - 1);
        const size_t kb = (size_t)(base + jc) * QKV_STRIDE + 1024;
        half8 k0v = *(const half8*)(qkv + kb + c0);
        half8 k1v = *(const half8*)(qkv + kb + 512 + c0);
        float d = dot16(q1, k1v, dot16(q0, k0v, 0.f));
#pragma unroll
        for (int off = 32; off > 0; off >>= 1)
            d += __shfl_xor(d, off);
        s[o] = (j == jc) ? d * 0.03125f : -3.0e38f;
    }

    float mx = s[0];
#pragma unroll
    for (int o = 1; o < W_; ++o) mx = fmaxf(mx, s[o]);
    float den = 0.f;
#pragma unroll
    for (int o = 0; o < W_; ++o) den += __expf(s[o] - mx);
    const float inv = 1.f / den;

    float acc0[8], acc1[8];
#pragma unroll
    for (int e = 0; e < 8; ++e) { acc0[e] = 0.f; acc1[e] = 0.f; }
#pragma unroll
    for (int o = 0; o < W_; ++o) {
        int j = t - HALF_ + o;
        int jc = min(max(j, 0), T_ - 1);
        const float wt = __expf(s[o] - mx) * inv;
        const size_t vb_ = (size_t)(base + jc) * QKV_STRIDE + 2048;
        half8 v0 = *(const half8*)(qkv + vb_ + c0);
        half8 v1 = *(const half8*)(qkv + vb_ + 512 + c0);
#pragma unroll
        for (int e = 0; e < 8; ++e) {
            acc0[e] += wt * (float)v0[e];
            acc1[e] += wt * (float)v1[e];
        }
    }

    const size_t crow = (size_t)(base + t) * C_;
    half8 o0, o1;
#pragma unroll
    for (int e = 0; e < 8; ++e) { o0[e] = (_Float16)acc0[e]; o1[e] = (_Float16)acc1[e]; }
    *(half8*)(ctx + crow + c0) = o0;
    *(half8*)(ctx + crow + 512 + c0) = o1;
}

// ---------------- host launch ----------------
extern "C" void kernel_launch(void* const* d_in, const int* in_sizes, int n_in,
                              void* d_out, int out_size, void* d_ws, size_t ws_size,
                              hipStream_t stream) {
    const float* x  = (const float*)d_in[0];
    const float* Wq = (const float*)d_in[1];
    const float* bq = (const float*)d_in[2];
    const float* Wk = (const float*)d_in[3];
    const float* bk = (const float*)d_in[4];
    const float* Wv = (const float*)d_in[5];
    const float* bv = (const float*)d_in[6];
    const float* Wo = (const float*)d_in[7];
    const float* bo = (const float*)d_in[8];
    float* out = (float*)d_out;

    u16* xh   = (u16*)d_ws;                         // 8M halves
    u16* wfq  = xh   + (size_t)M_ * C_;             // 3M  (Wq;Wk;Wv frag-major)
    u16* wfo  = wfq  + (size_t)3 * C_ * C_;         // 1M  (Wo frag-major)
    u16* qkvh = wfo  + (size_t)C_ * C_;             // 24M (M x 3072)
    u16* ctxh = qkvh + (size_t)M_ * QKV_STRIDE;     // 8M
    float* bcat = (float*)(ctxh + (size_t)M_ * C_); // 3072 floats

    prologue<<<8204, 256, 0, stream>>>(x, bq, bk, bv, xh, bcat);
    wfrag<<<2048, 256, 0, stream>>>(Wq, Wk, Wv, Wo, wfq, wfo);

    dim3 gqkv(QKV_STRIDE / 128, M_ / 128);   // (24, 64); 24%8==0 -> XCD = n%8
    gemm_nt_bfrag<<<gqkv, 256, 0, stream>>>(xh, wfq, bcat, qkvh, QKV_STRIDE, C_);

    attn_local<<<M_ / 4, 256, 0, stream>>>(qkvh, ctxh);   // 2048 blocks

    dim3 go(C_ / 64, M_ / 128);              // (16, 64); XCD = n%8
    gemm_nt_64_bfrag<<<go, 256, 0, stream>>>(ctxh, wfo, bo, out, C_, C_);
}